// Round 6
// baseline (441.239 us; speedup 1.0000x reference)
//
#include <hip/hip_runtime.h>

#define NROWS 65536   // B*T
#define DIM   256
#define VCB   2048

typedef _Float16 f16;
typedef _Float16 f16x8 __attribute__((ext_vector_type(8)));
typedef float    f32x4 __attribute__((ext_vector_type(4)));

// ---------------- ws layout (bytes) ----------------
// [0,        262144)  idx        int[NROWS]
// [262144,   270336)  hist       uint[VCB]
// [270336,   272384)  loss_part  double[256]
// [272384,   280576)  enorm      float[VCB]
// [524288,  1572864)  e_hi       f16[VCB*DIM]
// [1572864, 2621440)  e_lo       f16[VCB*DIM]
// z_hi/z_lo (64 MB) live in d_out's z_q region as scratch until the gather pass.

__device__ __forceinline__ void async16(void* lds, const void* g) {
  __builtin_amdgcn_global_load_lds(
      (const __attribute__((address_space(1))) void*)g,
      (__attribute__((address_space(3))) void*)lds, 16, 0, 0);
}

// fp32 -> (f16 hi, f16 lo) split, 4 elems/thread/iter, grid-stride
__global__ __launch_bounds__(256) void convert_kernel(
    const float4* __restrict__ src, short4* __restrict__ dhi,
    short4* __restrict__ dlo, int n4) {
  int stride = gridDim.x * 256;
  for (int i = blockIdx.x * 256 + threadIdx.x; i < n4; i += stride) {
    float4 v = src[i];
    union { f16 h[4]; short4 s; } H, L;
    H.h[0] = (f16)v.x; H.h[1] = (f16)v.y; H.h[2] = (f16)v.z; H.h[3] = (f16)v.w;
    L.h[0] = (f16)(v.x - (float)H.h[0]);
    L.h[1] = (f16)(v.y - (float)H.h[1]);
    L.h[2] = (f16)(v.z - (float)H.h[2]);
    L.h[3] = (f16)(v.w - (float)H.h[3]);
    dhi[i] = H.s; dlo[i] = L.s;
  }
}

// zero hist + loss partials, compute ||e_j||^2 (one wave per codebook row), fp32
__global__ __launch_bounds__(256) void prep_kernel(
    const float* __restrict__ e, float* __restrict__ enorm,
    unsigned int* __restrict__ hist, double* __restrict__ loss_part) {
  int tid = threadIdx.x;
  int gt = blockIdx.x * 256 + tid;
  if (gt < VCB) hist[gt] = 0u;
  if (gt < 256) loss_part[gt] = 0.0;
  int wid  = gt >> 6;
  int lane = tid & 63;
  if (wid < VCB) {
    const float4* row = (const float4*)(e + (size_t)wid * DIM);
    float4 v = row[lane];
    float s = v.x*v.x + v.y*v.y + v.z*v.z + v.w*v.w;
    #pragma unroll
    for (int off = 32; off; off >>= 1) s += __shfl_xor(s, off);
    if (lane == 0) enorm[wid] = s;
  }
}

// Fused split-f16 MFMA distance GEMM + row argmin.
// BM=128 x BN=64, BK=32, 256 threads = 4 waves (2x2), wave tile 64x32.
// LDS: 2 x 24KB dbuf -> 3 blocks/CU (12 waves/CU, 3/SIMD) for latency hiding.
// Counted vmcnt(6) pipeline: stage(t+1); vmcnt(6); barrier; compute; barrier.
__global__ __launch_bounds__(256, 3) void argmin_kernel(
    const f16* __restrict__ zh, const f16* __restrict__ zl,
    const f16* __restrict__ eh, const f16* __restrict__ el,
    const float* __restrict__ enorm,
    int* __restrict__ idx_out, unsigned int* __restrict__ hist) {
  // per buf (f16 units): Ah[0,4096) Al[4096,8192) Bh[8192,10240) Bl[10240,12288)
  __shared__ f16 lds[2][12288];
  __shared__ float sxv[2][64];   // cross-wave publish: [wr][row-in-strip]
  __shared__ int   sxi[2][64];

  const int tid  = threadIdx.x;
  const int wid  = tid >> 6;
  const int lane = tid & 63;
  const int wr   = wid >> 1;        // wave row 0..1 (64-row strip)
  const int wc   = wid & 1;         // wave col 0..1 (32-col strip)
  const int lrow = lane & 15;       // frag row/col index
  const int lq   = lane >> 4;       // k-chunk 0..3
  const int rbase = blockIdx.x * 128;

  // staging lane mapping: 16 rows x 4 chunks of 16B per wave-issue
  const int srow = lane >> 2;
  const int scol = lane & 3;

  // stage one (vt, kt) step's tiles into buffer b: 6 global_load_lds/thread.
  // XOR swizzle on within-row 16B chunk applied on the GLOBAL source
  // (LDS stays linear per global_load_lds rules), mirrored on frag reads.
  auto stage = [&](int b, int vt, int kt) {
    f16* base = lds[b];
    #pragma unroll
    for (int h = 0; h < 2; ++h) {           // A: chunks wid and wid+4
      int c    = wid + h * 4;
      int trow = c * 16 + srow;             // tile row 0..127
      int sw   = (trow >> 1) & 3;
      int koff = kt + ((scol ^ sw) << 3);
      size_t zoff = (size_t)(rbase + trow) * DIM + koff;
      async16(base +        c * 512, zh + zoff);
      async16(base + 4096 + c * 512, zl + zoff);
    }
    {                                        // B: chunk wid (64 rows total)
      int c    = wid;
      int trow = c * 16 + srow;             // codebook row 0..63
      int sw   = (trow >> 1) & 3;
      int koff = kt + ((scol ^ sw) << 3);
      size_t eoff = (size_t)(vt + trow) * DIM + koff;
      async16(base +  8192 + c * 512, eh + eoff);
      async16(base + 10240 + c * 512, el + eoff);
    }
  };

  float minv[4][4];
  int   mini[4][4];
  #pragma unroll
  for (int m = 0; m < 4; ++m)
    #pragma unroll
    for (int r = 0; r < 4; ++r) { minv[m][r] = 3.4e38f; mini[m][r] = 0; }

  const int NSTEP = (VCB / 64) * 8;   // 256 flattened (vt,kt) steps
  int cur = 0;
  stage(0, 0, 0);

  for (int vt = 0; vt < VCB; vt += 64) {
    f32x4 acc[4][2];
    #pragma unroll
    for (int m = 0; m < 4; ++m)
      #pragma unroll
      for (int n = 0; n < 2; ++n) {
        f32x4 zz = {0.f, 0.f, 0.f, 0.f};
        acc[m][n] = zz;
      }

    for (int ktep = 0; ktep < 8; ++ktep) {
      // prefetch next step into the other buffer; clamp keeps vmcnt uniform
      int nt = (vt >> 3) + ktep + 1;
      if (nt >= NSTEP) nt = 0;           // harmless re-stage of step 0 at the end
      stage(cur ^ 1, (nt >> 3) << 6, (nt & 7) << 5);

      // counted wait: only the 6 loads of the PREVIOUS step must have landed
      asm volatile("s_waitcnt vmcnt(6)" ::: "memory");
      asm volatile("s_barrier" ::: "memory");
      __builtin_amdgcn_sched_barrier(0);

      const f16* lAh = lds[cur];
      const f16* lAl = lds[cur] + 4096;
      const f16* lBh = lds[cur] + 8192;
      const f16* lBl = lds[cur] + 10240;

      const int cchunk = lq ^ ((lrow >> 1) & 3);
      f16x8 ah[4], al[4];
      #pragma unroll
      for (int m = 0; m < 4; ++m) {
        int row = wr * 64 + m * 16 + lrow;
        int off = row * 64 + cchunk * 16;
        ah[m] = *(const f16x8*)((const char*)lAh + off);
        al[m] = *(const f16x8*)((const char*)lAl + off);
      }
      __builtin_amdgcn_s_setprio(1);
      #pragma unroll
      for (int n = 0; n < 2; ++n) {
        int col = wc * 32 + n * 16 + lrow;
        int off = col * 64 + cchunk * 16;
        f16x8 bh = *(const f16x8*)((const char*)lBh + off);
        f16x8 bl = *(const f16x8*)((const char*)lBl + off);
        #pragma unroll
        for (int m = 0; m < 4; ++m) {
          acc[m][n] = __builtin_amdgcn_mfma_f32_16x16x32_f16(ah[m], bh, acc[m][n], 0, 0, 0);
          acc[m][n] = __builtin_amdgcn_mfma_f32_16x16x32_f16(ah[m], bl, acc[m][n], 0, 0, 0);
          acc[m][n] = __builtin_amdgcn_mfma_f32_16x16x32_f16(al[m], bh, acc[m][n], 0, 0, 0);
        }
      }
      __builtin_amdgcn_s_setprio(0);

      // WAR: all waves' LDS reads done before next step's stage overwrites cur
      __builtin_amdgcn_sched_barrier(0);
      asm volatile("s_barrier" ::: "memory");
      cur ^= 1;
    }

    // epilogue: C/D layout col=lane&15, row=(lane>>4)*4+reg (m89/m91)
    #pragma unroll
    for (int n = 0; n < 2; ++n) {
      int j = vt + wc * 32 + n * 16 + lrow;
      float en = enorm[j];
      #pragma unroll
      for (int m = 0; m < 4; ++m)
        #pragma unroll
        for (int r = 0; r < 4; ++r) {
          float s = fmaf(-2.f, acc[m][n][r], en);
          if (s < minv[m][r]) { minv[m][r] = s; mini[m][r] = j; }
        }
    }
  }

  // reduce across the 16 lanes (lane bits 0..3) sharing each row; first-idx tie-break
  #pragma unroll
  for (int off = 1; off < 16; off <<= 1) {
    #pragma unroll
    for (int m = 0; m < 4; ++m)
      #pragma unroll
      for (int r = 0; r < 4; ++r) {
        float ov = __shfl_xor(minv[m][r], off);
        int   oi = __shfl_xor(mini[m][r], off);
        if (ov < minv[m][r] || (ov == minv[m][r] && oi < mini[m][r])) {
          minv[m][r] = ov; mini[m][r] = oi;
        }
      }
  }

  // cross-wave merge: wc==1 publishes, wc==0 merges and is sole writer.
  if (wc == 1 && lrow == 0) {
    #pragma unroll
    for (int m = 0; m < 4; ++m)
      #pragma unroll
      for (int r = 0; r < 4; ++r) {
        int li = m * 16 + lq * 4 + r;
        sxv[wr][li] = minv[m][r];
        sxi[wr][li] = mini[m][r];
      }
  }
  __syncthreads();
  if (wc == 0 && lrow == 0) {
    #pragma unroll
    for (int m = 0; m < 4; ++m)
      #pragma unroll
      for (int r = 0; r < 4; ++r) {
        int li = m * 16 + lq * 4 + r;
        float ov = sxv[wr][li];
        int   oi = sxi[wr][li];
        float v  = minv[m][r];
        int   bi = mini[m][r];
        if (ov < v || (ov == v && oi < bi)) { v = ov; bi = oi; }
        idx_out[rbase + wr * 64 + li] = bi;
        atomicAdd(&hist[bi], 1u);
      }
  }
}

// gather z_q = e[idx], write z_q_st + float indices, accumulate sum((z-z_q)^2)
__global__ __launch_bounds__(256) void gather_loss_kernel(
    const float* __restrict__ z, const float* __restrict__ e,
    const int* __restrict__ idx, float* __restrict__ zq_out,
    float* __restrict__ idxf_out, double* __restrict__ loss_part) {
  __shared__ float wsum[4];
  int tid  = threadIdx.x;
  int w    = tid >> 6;
  int lane = tid & 63;
  int n    = blockIdx.x * 4 + w;

  int ci = idx[n];
  const float4* zr = (const float4*)(z + (size_t)n  * DIM);
  const float4* er = (const float4*)(e + (size_t)ci * DIM);
  float4 zv = zr[lane];
  float4 ev = er[lane];
  ((float4*)(zq_out + (size_t)n * DIM))[lane] = ev;
  if (lane == 0) idxf_out[n] = (float)ci;

  float dx = zv.x - ev.x, dy = zv.y - ev.y, dz = zv.z - ev.z, dw = zv.w - ev.w;
  float s = dx*dx + dy*dy + dz*dz + dw*dw;
  #pragma unroll
  for (int off = 32; off; off >>= 1) s += __shfl_xor(s, off);
  if (lane == 0) wsum[w] = s;
  __syncthreads();
  if (tid == 0) {
    float bs = wsum[0] + wsum[1] + wsum[2] + wsum[3];
    atomicAdd(&loss_part[blockIdx.x & 255], (double)bs);
  }
}

__global__ __launch_bounds__(256) void finalize_kernel(
    const unsigned int* __restrict__ hist, const double* __restrict__ loss_part,
    float* __restrict__ out) {
  __shared__ double lsh[4];
  __shared__ float  hsh[4];
  __shared__ float  denom_sh;
  int tid = threadIdx.x, lane = tid & 63, w = tid >> 6;

  float hs = 0.f;
  for (int j = tid; j < VCB; j += 256) hs += (float)hist[j];
  double ls = loss_part[tid];
  #pragma unroll
  for (int off = 32; off; off >>= 1) {
    hs += __shfl_xor(hs, off);
    ls += __shfl_xor(ls, off);
  }
  if (lane == 0) { lsh[w] = ls; hsh[w] = hs; }
  __syncthreads();
  if (tid == 0) {
    double lt = lsh[0] + lsh[1] + lsh[2] + lsh[3];
    float  ht = hsh[0] + hsh[1] + hsh[2] + hsh[3];
    out[0] = (float)(lt / (double)((size_t)NROWS * DIM));
    denom_sh = ht + 1e-8f;
  }
  __syncthreads();
  float denom = denom_sh;
  float* prob = out + 1 + (size_t)NROWS * DIM + NROWS;
  for (int j = tid; j < VCB; j += 256) prob[j] = (float)hist[j] / denom;
}

extern "C" void kernel_launch(void* const* d_in, const int* in_sizes, int n_in,
                              void* d_out, int out_size, void* d_ws, size_t ws_size,
                              hipStream_t stream) {
  (void)in_sizes; (void)n_in; (void)out_size; (void)ws_size;
  const float* z = (const float*)d_in[0];
  const float* e = (const float*)d_in[1];
  float* out = (float*)d_out;
  char*  ws  = (char*)d_ws;

  int*          idx       = (int*)ws;
  unsigned int* hist      = (unsigned int*)(ws + 262144);
  double*       loss_part = (double*)(ws + 270336);
  float*        enorm     = (float*)(ws + 272384);
  f16*          e_hi      = (f16*)(ws + 524288);
  f16*          e_lo      = (f16*)(ws + 1572864);

  // z split lives in d_out's z_q region (scratch until gather pass).
  f16* z_hi = (f16*)(out + 4);
  f16* z_lo = z_hi + (size_t)NROWS * DIM;

  float* out_zq  = out + 1;
  float* out_idx = out + 1 + (size_t)NROWS * DIM;

  convert_kernel<<<1024, 256, 0, stream>>>(
      (const float4*)z, (short4*)z_hi, (short4*)z_lo, NROWS * DIM / 4);
  convert_kernel<<<128, 256, 0, stream>>>(
      (const float4*)e, (short4*)e_hi, (short4*)e_lo, VCB * DIM / 4);
  prep_kernel<<<512, 256, 0, stream>>>(e, enorm, hist, loss_part);
  argmin_kernel<<<NROWS / 128, 256, 0, stream>>>(
      z_hi, z_lo, e_hi, e_lo, enorm, idx, hist);
  gather_loss_kernel<<<NROWS / 4, 256, 0, stream>>>(
      z, e, idx, out_zq, out_idx, loss_part);
  finalize_kernel<<<1, 256, 0, stream>>>(hist, loss_part, out);
}

// Round 7
// 275.672 us; speedup vs baseline: 1.6006x; 1.6006x over previous
//
#include <hip/hip_runtime.h>

#define NROWS 65536   // B*T
#define DIM   256
#define VCB   2048

typedef _Float16 f16;
typedef _Float16 f16x8 __attribute__((ext_vector_type(8)));
typedef float    f32x4 __attribute__((ext_vector_type(4)));

// ---------------- ws layout (bytes) ----------------
// [0,        262144)  idx        int[NROWS]
// [262144,   270336)  hist       uint[VCB]
// [270336,   272384)  loss_part  double[256]
// [272384,   280576)  enorm      float[VCB]
// [524288,  1572864)  e_hi       f16[VCB*DIM]
// [1572864, 2621440)  e_lo       f16[VCB*DIM]
// z_hi/z_lo (64 MB) live in d_out's z_q region as scratch until the gather pass.

__device__ __forceinline__ void async16(void* lds, const void* g) {
  __builtin_amdgcn_global_load_lds(
      (const __attribute__((address_space(1))) void*)g,
      (__attribute__((address_space(3))) void*)lds, 16, 0, 0);
}

// fp32 -> (f16 hi, f16 lo) split, 4 elems/thread/iter, grid-stride
__global__ __launch_bounds__(256) void convert_kernel(
    const float4* __restrict__ src, short4* __restrict__ dhi,
    short4* __restrict__ dlo, int n4) {
  int stride = gridDim.x * 256;
  for (int i = blockIdx.x * 256 + threadIdx.x; i < n4; i += stride) {
    float4 v = src[i];
    union { f16 h[4]; short4 s; } H, L;
    H.h[0] = (f16)v.x; H.h[1] = (f16)v.y; H.h[2] = (f16)v.z; H.h[3] = (f16)v.w;
    L.h[0] = (f16)(v.x - (float)H.h[0]);
    L.h[1] = (f16)(v.y - (float)H.h[1]);
    L.h[2] = (f16)(v.z - (float)H.h[2]);
    L.h[3] = (f16)(v.w - (float)H.h[3]);
    dhi[i] = H.s; dlo[i] = L.s;
  }
}

// zero hist + loss partials, compute ||e_j||^2 (one wave per codebook row), fp32
__global__ __launch_bounds__(256) void prep_kernel(
    const float* __restrict__ e, float* __restrict__ enorm,
    unsigned int* __restrict__ hist, double* __restrict__ loss_part) {
  int tid = threadIdx.x;
  int gt = blockIdx.x * 256 + tid;
  if (gt < VCB) hist[gt] = 0u;
  if (gt < 256) loss_part[gt] = 0.0;
  int wid  = gt >> 6;
  int lane = tid & 63;
  if (wid < VCB) {
    const float4* row = (const float4*)(e + (size_t)wid * DIM);
    float4 v = row[lane];
    float s = v.x*v.x + v.y*v.y + v.z*v.z + v.w*v.w;
    #pragma unroll
    for (int off = 32; off; off >>= 1) s += __shfl_xor(s, off);
    if (lane == 0) enorm[wid] = s;
  }
}

// Fused split-f16 MFMA distance GEMM + row argmin.
// Superstep = 256 codebook cols: A-tile (z) staged ONCE per kt and its LDS
// fragments reused in registers for BOTH 128-col halves -> z HBM traffic
// halved vs r5 and LDS A-read traffic -25%. Counted vmcnt(8) pipeline,
// A-dbuf keyed by kt parity, B-dbuf keyed by body-step parity.
__global__ __launch_bounds__(256, 2) void argmin_kernel(
    const f16* __restrict__ zh, const f16* __restrict__ zl,
    const f16* __restrict__ eh, const f16* __restrict__ el,
    const float* __restrict__ enorm,
    int* __restrict__ idx_out, unsigned int* __restrict__ hist) {
  // per buffer: hi tile [128][32] f16 at [0,4096), lo at [4096,8192)
  __shared__ f16 ldsA[2][8192];
  __shared__ f16 ldsB[2][8192];
  __shared__ float sxv[2][64];   // cross-wave publish: [wr][row-in-strip]
  __shared__ int   sxi[2][64];

  const int tid  = threadIdx.x;
  const int wid  = tid >> 6;
  const int lane = tid & 63;
  const int wr   = wid >> 1;        // wave row 0..1 (64-row strip)
  const int wc   = wid & 1;         // wave col 0..1 (64-col strip within a half)
  const int lrow = lane & 15;       // frag row/col index
  const int lq   = lane >> 4;       // k-chunk 0..3
  const int rbase = blockIdx.x * 128;

  // staging lane mapping: 16 rows x 4 chunks of 16B per wave-issue
  const int srow = lane >> 2;
  const int scol = lane & 3;

  // XOR swizzle on within-row 16B chunk applied on the GLOBAL source
  // (LDS stays linear per global_load_lds rules), mirrored on frag reads.
  auto stageA = [&](int ab, int kt) {   // 4 loads/thread
    f16* base = ldsA[ab];
    #pragma unroll
    for (int h = 0; h < 2; ++h) {
      int c    = wid + h * 4;
      int trow = c * 16 + srow;
      int sw   = (trow >> 1) & 3;
      int koff = (kt << 5) + ((scol ^ sw) << 3);
      size_t zoff = (size_t)(rbase + trow) * DIM + koff;
      async16(base +        c * 512, zh + zoff);
      async16(base + 4096 + c * 512, zl + zoff);
    }
  };
  auto stageB = [&](int bb, int vcol, int kt) {   // 4 loads/thread
    f16* base = ldsB[bb];
    #pragma unroll
    for (int h = 0; h < 2; ++h) {
      int c    = wid + h * 4;
      int trow = c * 16 + srow;
      int sw   = (trow >> 1) & 3;
      int koff = (kt << 5) + ((scol ^ sw) << 3);
      size_t eoff = (size_t)(vcol + trow) * DIM + koff;
      async16(base +        c * 512, eh + eoff);
      async16(base + 4096 + c * 512, el + eoff);
    }
  };

  float minv[4][4];
  int   mini[4][4];
  #pragma unroll
  for (int m = 0; m < 4; ++m)
    #pragma unroll
    for (int r = 0; r < 4; ++r) { minv[m][r] = 3.4e38f; mini[m][r] = 0; }

  const int cchunk = lq ^ ((lrow >> 1) & 3);

  int sB = 0;
  stageA(0, 0);
  stageB(0, 0, 0);

  for (int v2 = 0; v2 < VCB / 256; ++v2) {
    const int vt2 = v2 << 8;
    f32x4 acc[2][4][4];
    #pragma unroll
    for (int hh = 0; hh < 2; ++hh)
      #pragma unroll
      for (int m = 0; m < 4; ++m)
        #pragma unroll
        for (int n = 0; n < 4; ++n) {
          f32x4 zz = {0.f, 0.f, 0.f, 0.f};
          acc[hh][m][n] = zz;
        }

    for (int kt = 0; kt < 8; ++kt) {
      const int a = kt & 1;

      // ---------- body-step h0: consume ldsA[a], ldsB[sB] ----------
      // issue order matters for vmcnt accounting: B(h1) first, then A(kt+1)
      stageB(sB ^ 1, vt2 + 128, kt);
      stageA(a ^ 1, (kt + 1) & 7);   // kt=7 wraps to A(0): next superstep's prefetch
      asm volatile("s_waitcnt vmcnt(8)" ::: "memory");
      asm volatile("s_barrier" ::: "memory");
      __builtin_amdgcn_sched_barrier(0);

      f16x8 ah[4], al[4];
      {
        const char* base = (const char*)ldsA[a];
        #pragma unroll
        for (int m = 0; m < 4; ++m) {
          int row = wr * 64 + m * 16 + lrow;
          int off = row * 64 + cchunk * 16;
          ah[m] = *(const f16x8*)(base + off);
          al[m] = *(const f16x8*)(base + 8192 + off);
        }
      }
      {
        const char* bbase = (const char*)ldsB[sB];
        __builtin_amdgcn_s_setprio(1);
        #pragma unroll
        for (int n = 0; n < 4; ++n) {
          int col = wc * 64 + n * 16 + lrow;
          int off = col * 64 + cchunk * 16;
          f16x8 bh = *(const f16x8*)(bbase + off);
          f16x8 bl = *(const f16x8*)(bbase + 8192 + off);
          #pragma unroll
          for (int m = 0; m < 4; ++m) {
            acc[0][m][n] = __builtin_amdgcn_mfma_f32_16x16x32_f16(ah[m], bh, acc[0][m][n], 0, 0, 0);
            acc[0][m][n] = __builtin_amdgcn_mfma_f32_16x16x32_f16(ah[m], bl, acc[0][m][n], 0, 0, 0);
            acc[0][m][n] = __builtin_amdgcn_mfma_f32_16x16x32_f16(al[m], bh, acc[0][m][n], 0, 0, 0);
          }
        }
        __builtin_amdgcn_s_setprio(0);
      }
      __builtin_amdgcn_sched_barrier(0);
      asm volatile("s_barrier" ::: "memory");
      sB ^= 1;

      // ---------- body-step h1: consume ldsB[sB]; A frags already in regs ----
      {
        int nkt = kt + 1, nvt = vt2;
        if (nkt == 8) { nkt = 0; nvt = vt2 + 256; if (nvt == VCB) nvt = 0; }
        stageB(sB ^ 1, nvt, nkt);
      }
      asm volatile("s_waitcnt vmcnt(8)" ::: "memory");
      asm volatile("s_barrier" ::: "memory");
      __builtin_amdgcn_sched_barrier(0);

      {
        const char* bbase = (const char*)ldsB[sB];
        __builtin_amdgcn_s_setprio(1);
        #pragma unroll
        for (int n = 0; n < 4; ++n) {
          int col = wc * 64 + n * 16 + lrow;
          int off = col * 64 + cchunk * 16;
          f16x8 bh = *(const f16x8*)(bbase + off);
          f16x8 bl = *(const f16x8*)(bbase + 8192 + off);
          #pragma unroll
          for (int m = 0; m < 4; ++m) {
            acc[1][m][n] = __builtin_amdgcn_mfma_f32_16x16x32_f16(ah[m], bh, acc[1][m][n], 0, 0, 0);
            acc[1][m][n] = __builtin_amdgcn_mfma_f32_16x16x32_f16(ah[m], bl, acc[1][m][n], 0, 0, 0);
            acc[1][m][n] = __builtin_amdgcn_mfma_f32_16x16x32_f16(al[m], bh, acc[1][m][n], 0, 0, 0);
          }
        }
        __builtin_amdgcn_s_setprio(0);
      }
      __builtin_amdgcn_sched_barrier(0);
      asm volatile("s_barrier" ::: "memory");
      sB ^= 1;
    }

    // epilogue: C/D layout col=lane&15, row=(lane>>4)*4+reg (m89/m91)
    #pragma unroll
    for (int hh = 0; hh < 2; ++hh)
      #pragma unroll
      for (int n = 0; n < 4; ++n) {
        int j = vt2 + hh * 128 + wc * 64 + n * 16 + lrow;
        float en = enorm[j];
        #pragma unroll
        for (int m = 0; m < 4; ++m)
          #pragma unroll
          for (int r = 0; r < 4; ++r) {
            float s = fmaf(-2.f, acc[hh][m][n][r], en);
            if (s < minv[m][r]) { minv[m][r] = s; mini[m][r] = j; }
          }
      }
  }

  // reduce across the 16 lanes (lane bits 0..3) sharing each row; first-idx tie-break
  #pragma unroll
  for (int off = 1; off < 16; off <<= 1) {
    #pragma unroll
    for (int m = 0; m < 4; ++m)
      #pragma unroll
      for (int r = 0; r < 4; ++r) {
        float ov = __shfl_xor(minv[m][r], off);
        int   oi = __shfl_xor(mini[m][r], off);
        if (ov < minv[m][r] || (ov == minv[m][r] && oi < mini[m][r])) {
          minv[m][r] = ov; mini[m][r] = oi;
        }
      }
  }

  // cross-wave merge: wc==1 publishes, wc==0 merges and is sole writer.
  if (wc == 1 && lrow == 0) {
    #pragma unroll
    for (int m = 0; m < 4; ++m)
      #pragma unroll
      for (int r = 0; r < 4; ++r) {
        int li = m * 16 + lq * 4 + r;
        sxv[wr][li] = minv[m][r];
        sxi[wr][li] = mini[m][r];
      }
  }
  __syncthreads();
  if (wc == 0 && lrow == 0) {
    #pragma unroll
    for (int m = 0; m < 4; ++m)
      #pragma unroll
      for (int r = 0; r < 4; ++r) {
        int li = m * 16 + lq * 4 + r;
        float ov = sxv[wr][li];
        int   oi = sxi[wr][li];
        float v  = minv[m][r];
        int   bi = mini[m][r];
        if (ov < v || (ov == v && oi < bi)) { v = ov; bi = oi; }
        idx_out[rbase + wr * 64 + li] = bi;
        atomicAdd(&hist[bi], 1u);
      }
  }
}

// gather z_q = e[idx], write z_q_st + float indices, accumulate sum((z-z_q)^2)
__global__ __launch_bounds__(256) void gather_loss_kernel(
    const float* __restrict__ z, const float* __restrict__ e,
    const int* __restrict__ idx, float* __restrict__ zq_out,
    float* __restrict__ idxf_out, double* __restrict__ loss_part) {
  __shared__ float wsum[4];
  int tid  = threadIdx.x;
  int w    = tid >> 6;
  int lane = tid & 63;
  int n    = blockIdx.x * 4 + w;

  int ci = idx[n];
  const float4* zr = (const float4*)(z + (size_t)n  * DIM);
  const float4* er = (const float4*)(e + (size_t)ci * DIM);
  float4 zv = zr[lane];
  float4 ev = er[lane];
  ((float4*)(zq_out + (size_t)n * DIM))[lane] = ev;
  if (lane == 0) idxf_out[n] = (float)ci;

  float dx = zv.x - ev.x, dy = zv.y - ev.y, dz = zv.z - ev.z, dw = zv.w - ev.w;
  float s = dx*dx + dy*dy + dz*dz + dw*dw;
  #pragma unroll
  for (int off = 32; off; off >>= 1) s += __shfl_xor(s, off);
  if (lane == 0) wsum[w] = s;
  __syncthreads();
  if (tid == 0) {
    float bs = wsum[0] + wsum[1] + wsum[2] + wsum[3];
    atomicAdd(&loss_part[blockIdx.x & 255], (double)bs);
  }
}

__global__ __launch_bounds__(256) void finalize_kernel(
    const unsigned int* __restrict__ hist, const double* __restrict__ loss_part,
    float* __restrict__ out) {
  __shared__ double lsh[4];
  __shared__ float  hsh[4];
  __shared__ float  denom_sh;
  int tid = threadIdx.x, lane = tid & 63, w = tid >> 6;

  float hs = 0.f;
  for (int j = tid; j < VCB; j += 256) hs += (float)hist[j];
  double ls = loss_part[tid];
  #pragma unroll
  for (int off = 32; off; off >>= 1) {
    hs += __shfl_xor(hs, off);
    ls += __shfl_xor(ls, off);
  }
  if (lane == 0) { lsh[w] = ls; hsh[w] = hs; }
  __syncthreads();
  if (tid == 0) {
    double lt = lsh[0] + lsh[1] + lsh[2] + lsh[3];
    float  ht = hsh[0] + hsh[1] + hsh[2] + hsh[3];
    out[0] = (float)(lt / (double)((size_t)NROWS * DIM));
    denom_sh = ht + 1e-8f;
  }
  __syncthreads();
  float denom = denom_sh;
  float* prob = out + 1 + (size_t)NROWS * DIM + NROWS;
  for (int j = tid; j < VCB; j += 256) prob[j] = (float)hist[j] / denom;
}

extern "C" void kernel_launch(void* const* d_in, const int* in_sizes, int n_in,
                              void* d_out, int out_size, void* d_ws, size_t ws_size,
                              hipStream_t stream) {
  (void)in_sizes; (void)n_in; (void)out_size; (void)ws_size;
  const float* z = (const float*)d_in[0];
  const float* e = (const float*)d_in[1];
  float* out = (float*)d_out;
  char*  ws  = (char*)d_ws;

  int*          idx       = (int*)ws;
  unsigned int* hist      = (unsigned int*)(ws + 262144);
  double*       loss_part = (double*)(ws + 270336);
  float*        enorm     = (float*)(ws + 272384);
  f16*          e_hi      = (f16*)(ws + 524288);
  f16*          e_lo      = (f16*)(ws + 1572864);

  // z split lives in d_out's z_q region (scratch until gather pass).
  f16* z_hi = (f16*)(out + 4);
  f16* z_lo = z_hi + (size_t)NROWS * DIM;

  float* out_zq  = out + 1;
  float* out_idx = out + 1 + (size_t)NROWS * DIM;

  convert_kernel<<<1024, 256, 0, stream>>>(
      (const float4*)z, (short4*)z_hi, (short4*)z_lo, NROWS * DIM / 4);
  convert_kernel<<<128, 256, 0, stream>>>(
      (const float4*)e, (short4*)e_hi, (short4*)e_lo, VCB * DIM / 4);
  prep_kernel<<<512, 256, 0, stream>>>(e, enorm, hist, loss_part);
  argmin_kernel<<<NROWS / 128, 256, 0, stream>>>(
      z_hi, z_lo, e_hi, e_lo, enorm, idx, hist);
  gather_loss_kernel<<<NROWS / 4, 256, 0, stream>>>(
      z, e, idx, out_zq, out_idx, loss_part);
  finalize_kernel<<<1, 256, 0, stream>>>(hist, loss_part, out);
}